// Round 2
// baseline (530.890 us; speedup 1.0000x reference)
//
#include <hip/hip_runtime.h>
#include <cstdint>
#include <cstddef>

// CompressiveMemory: B=2,H=32,T=4096,D=128 fp32.
// out  = phi(Q)@M / max(phi(Q)@z, eps)      (per b,h)
// Mnew = M + sum_t phiKb(t) outer Vb(t)     (phiKb/Vb are b-means)
// znew = z + sum_t phiKb(t)

typedef __bf16 bf16x8 __attribute__((ext_vector_type(8)));
typedef float  f32x4  __attribute__((ext_vector_type(4)));
typedef unsigned short us8v __attribute__((ext_vector_type(8)));

#define NB 2
#define NH 32
#define NT 4096
#define ND 128
#define NC 8            // split-K chunks for update GEMM
#define TCH (NT / NC)   // 512 t per chunk
#define NUPD (NH * NC)  // 256 update blocks (scheduled first: long poles)
#define NOUT (NB * NH * (NT / 128))  // 2048 out blocks
#define EPSF 1e-6f

__device__ __forceinline__ float phi_f(float x) {
    // elu(x)+1: x>0 -> x+1 ; x<=0 -> exp(x)
    return x > 0.0f ? x + 1.0f : __expf(x);
}

__device__ __forceinline__ unsigned short f2bfn(float f) {
    union { __bf16 h; unsigned short u; } c;
    c.h = (__bf16)f;  // native RNE cvt on gfx950
    return c.u;
}

// native packed convert path: compiler fuses adjacent pairs to v_cvt_pk_bf16_f32
__device__ __forceinline__ bf16x8 cvt8(float4 a, float4 b) {
    bf16x8 r;
    r[0] = (__bf16)a.x; r[1] = (__bf16)a.y; r[2] = (__bf16)a.z; r[3] = (__bf16)a.w;
    r[4] = (__bf16)b.x; r[5] = (__bf16)b.y; r[6] = (__bf16)b.z; r[7] = (__bf16)b.w;
    return r;
}

__device__ __forceinline__ bf16x8 cvt8phi(float4 a, float4 b) {
    bf16x8 r;
    r[0] = (__bf16)phi_f(a.x); r[1] = (__bf16)phi_f(a.y);
    r[2] = (__bf16)phi_f(a.z); r[3] = (__bf16)phi_f(a.w);
    r[4] = (__bf16)phi_f(b.x); r[5] = (__bf16)phi_f(b.y);
    r[6] = (__bf16)phi_f(b.z); r[7] = (__bf16)phi_f(b.w);
    return r;
}

// ---------------------------------------------------------------- k_prep
// Mt[h][e][d] = bf16(M[h][d][e]). M is 2MB -> gather reads are L2-resident.
__global__ __launch_bounds__(256) void k_prep(const float* __restrict__ M,
                                              unsigned short* __restrict__ Mt) {
    int idx = blockIdx.x * 256 + threadIdx.x;  // < 32*128*128
    int h = idx >> 14, rem = idx & 16383;
    int e = rem >> 7, d = rem & 127;
    Mt[idx] = f2bfn(M[(h << 14) + (d << 7) + e]);
}

// ---------------------------------------------------------------- upd body
// C[d][e] = sum_{t in chunk} phiKb[t][d] * Vb[t][e]   (k = t, MFMA)
// Staging accumulates the batch SUM (no 0.5 muls); exact 0.25/0.5
// power-of-2 scales applied at the partial write (numerically identical).
// LDS layout: Kl/Vl [d][t] with XOR swizzle: element (d,t) stored at
// t-group (t>>3) ^ ((d>>2)&7), offset t&7, row stride 64 u16.
// -> ds_write_b128 / ds_read_b128 both near-conflict-free, 16B aligned.
__device__ __forceinline__ void upd_body(int blk, const float* __restrict__ K,
                                         const float* __restrict__ V,
                                         float* __restrict__ part,
                                         float* __restrict__ zpart,
                                         unsigned short* smem) {
    const int tid = threadIdx.x;
    const int h = blk >> 3, ch = blk & 7;
    unsigned short* Kl = smem;          // 128 x 64 (swizzled)
    unsigned short* Vl = smem + 8192;   // 128 x 64

    const size_t bstr = (size_t)NH * NT * ND;
    const float* K0 = K + (size_t)h * NT * ND + (size_t)ch * TCH * ND;
    const float* K1 = K0 + bstr;
    const float* V0 = V + (size_t)h * NT * ND + (size_t)ch * TCH * ND;
    const float* V1 = V0 + bstr;

    const int L = tid & 31, d0 = L << 2, tb = tid >> 5;  // thread: 4 d x 8 t
    const int lane = tid & 63, wave = tid >> 6;
    const int mw = (wave & 1) << 6, nw = (wave >> 1) << 6;
    const int l15 = lane & 15, qd = lane >> 4;
    const int grp = tb ^ (L & 7);  // swizzled t-group for writes ((d>>2)&7 == L&7)

    float zp0 = 0.f, zp1 = 0.f, zp2 = 0.f, zp3 = 0.f;
    f32x4 acc[4][4];
#pragma unroll
    for (int a = 0; a < 4; ++a)
#pragma unroll
        for (int b = 0; b < 4; ++b) acc[a][b] = (f32x4){0.f, 0.f, 0.f, 0.f};

    for (int st = 0; st < TCH / 64; ++st) {
        bf16x8 kpu[4], vpu[4];
#pragma unroll
        for (int i = 0; i < 8; ++i) {  // 8 consecutive t rows
            size_t off = ((size_t)(st * 64 + tb * 8 + i)) * ND + d0;
            float4 a0 = *(const float4*)(K0 + off);
            float4 a1 = *(const float4*)(K1 + off);
            float4 b0 = *(const float4*)(V0 + off);
            float4 b1 = *(const float4*)(V1 + off);
            float p0 = phi_f(a0.x) + phi_f(a1.x);
            float p1 = phi_f(a0.y) + phi_f(a1.y);
            float p2 = phi_f(a0.z) + phi_f(a1.z);
            float p3 = phi_f(a0.w) + phi_f(a1.w);
            zp0 += p0; zp1 += p1; zp2 += p2; zp3 += p3;
            kpu[0][i] = (__bf16)p0; kpu[1][i] = (__bf16)p1;
            kpu[2][i] = (__bf16)p2; kpu[3][i] = (__bf16)p3;
            vpu[0][i] = (__bf16)(b0.x + b1.x);
            vpu[1][i] = (__bf16)(b0.y + b1.y);
            vpu[2][i] = (__bf16)(b0.z + b1.z);
            vpu[3][i] = (__bf16)(b0.w + b1.w);
        }
        __syncthreads();  // previous sub-tile's readers done
#pragma unroll
        for (int j = 0; j < 4; ++j) {
            *(bf16x8*)&Kl[(d0 + j) * 64 + grp * 8] = kpu[j];
            *(bf16x8*)&Vl[(d0 + j) * 64 + grp * 8] = vpu[j];
        }
        __syncthreads();
#pragma unroll
        for (int kk = 0; kk < 2; ++kk) {
            bf16x8 af[4], bv[4];
#pragma unroll
            for (int im = 0; im < 4; ++im) {
                int d = mw + im * 16 + l15;
                int sg = (kk * 4 + qd) ^ ((d >> 2) & 7);
                af[im] = *(const bf16x8*)&Kl[d * 64 + sg * 8];
            }
#pragma unroll
            for (int in = 0; in < 4; ++in) {
                int e = nw + in * 16 + l15;
                int sg = (kk * 4 + qd) ^ ((e >> 2) & 7);
                bv[in] = *(const bf16x8*)&Vl[e * 64 + sg * 8];
            }
#pragma unroll
            for (int im = 0; im < 4; ++im)
#pragma unroll
                for (int in = 0; in < 4; ++in)
                    acc[im][in] = __builtin_amdgcn_mfma_f32_16x16x32_bf16(
                        af[im], bv[in], acc[im][in], 0, 0, 0);
        }
    }

    // z reduction: overlay zacc onto smem (Kl region) once all readers done.
    __syncthreads();
    float* zacc = (float*)smem;
    if (tid < 128) zacc[tid] = 0.0f;
    __syncthreads();
    atomicAdd(&zacc[d0 + 0], zp0);
    atomicAdd(&zacc[d0 + 1], zp1);
    atomicAdd(&zacc[d0 + 2], zp2);
    atomicAdd(&zacc[d0 + 3], zp3);
    __syncthreads();
    if (tid < 128) zpart[((size_t)h * NC + ch) * 128 + tid] = 0.5f * zacc[tid];

    float* pb = part + ((size_t)h * NC + ch) * 16384;
#pragma unroll
    for (int im = 0; im < 4; ++im)
#pragma unroll
        for (int in = 0; in < 4; ++in) {
            int col = nw + in * 16 + l15;
#pragma unroll
            for (int rg = 0; rg < 4; ++rg) {
                int row = mw + im * 16 + qd * 4 + rg;  // d index
                pb[(size_t)row * ND + col] = 0.25f * acc[im][in][rg];
            }
        }
}

// ---------------------------------------------------------------- out body
// C(128x128) = phiQ @ M per (b,h,t-tile). A-fragments straight from global
// (phi in-register); norm = phiQ . z via MFMA against z-broadcast B-frag.
// M^T in LDS, stride 128 u16 + XOR chunk swizzle (chunk c of row e stored at
// c ^ (e&7)): write and read both 2-way max bank aliasing (free), 32768 B.
__device__ __forceinline__ void out_body(int blk, const float* __restrict__ Q,
                                         const unsigned short* __restrict__ Mt,
                                         const float* __restrict__ z,
                                         float* __restrict__ out,
                                         unsigned short* smem) {
    const int tid = threadIdx.x;
    const int tile = blk & 31, bh = blk >> 5, h = bh & 31;
    const float* Qb = Q + ((size_t)bh * NT + (size_t)tile * 128) * ND;
    unsigned short* Bs = smem;  // [e][chunk ^ (e&7)], stride 128 u16

    {
        const us8v* src = (const us8v*)(Mt + (size_t)h * 16384);
#pragma unroll
        for (int i = 0; i < 8; ++i) {
            int idx = i * 256 + tid;  // 16B chunk id
            int e = idx >> 4, d8 = idx & 15;
            *(us8v*)&Bs[e * 128 + ((d8 ^ (e & 7)) << 3)] = src[idx];
        }
    }
    const int lane = tid & 63, wave = tid >> 6;
    const int mw = (wave & 1) << 6, nw = (wave >> 1) << 6;
    const int l15 = lane & 15, qd = lane >> 4;
    const int s7 = l15 & 7;  // e&7 == l15&7 for all our e

    bf16x8 zf[4];  // z broadcast across columns -> accN col = norm(row)
#pragma unroll
    for (int kk = 0; kk < 4; ++kk) {
        const float* zp = z + h * ND + kk * 32 + qd * 8;
        zf[kk] = cvt8(*(const float4*)zp, *(const float4*)(zp + 4));
    }
    __syncthreads();

    f32x4 acc[4][4], accN[4];
#pragma unroll
    for (int a = 0; a < 4; ++a) {
        accN[a] = (f32x4){0.f, 0.f, 0.f, 0.f};
#pragma unroll
        for (int b = 0; b < 4; ++b) acc[a][b] = (f32x4){0.f, 0.f, 0.f, 0.f};
    }

#pragma unroll
    for (int im = 0; im < 4; ++im) {
        int row = mw + im * 16 + l15;
        const float* qr = Qb + (size_t)row * ND;
        bf16x8 af[4];
#pragma unroll
        for (int kk = 0; kk < 4; ++kk) {
            const float* qp = qr + kk * 32 + qd * 8;
            af[kk] = cvt8phi(*(const float4*)qp, *(const float4*)(qp + 4));
        }
#pragma unroll
        for (int kk = 0; kk < 4; ++kk)
            accN[im] = __builtin_amdgcn_mfma_f32_16x16x32_bf16(
                af[kk], zf[kk], accN[im], 0, 0, 0);
#pragma unroll
        for (int in = 0; in < 4; ++in) {
            int e = nw + in * 16 + l15;
#pragma unroll
            for (int kk = 0; kk < 4; ++kk) {
                bf16x8 bv = *(const bf16x8*)&Bs[e * 128 + ((((kk << 2) | qd) ^ s7) << 3)];
                acc[im][in] = __builtin_amdgcn_mfma_f32_16x16x32_bf16(
                    af[kk], bv, acc[im][in], 0, 0, 0);
            }
        }
    }

    float* outb = out + ((size_t)bh * NT + (size_t)tile * 128) * ND;
#pragma unroll
    for (int im = 0; im < 4; ++im) {
#pragma unroll
        for (int rg = 0; rg < 4; ++rg) {
            float inv = __builtin_amdgcn_rcpf(fmaxf(accN[im][rg], EPSF));
            int row = mw + im * 16 + qd * 4 + rg;
#pragma unroll
            for (int in = 0; in < 4; ++in) {
                int col = nw + in * 16 + l15;
                outb[(size_t)row * ND + col] = acc[im][in][rg] * inv;
            }
        }
    }
}

// ---------------------------------------------------------------- k_main
__global__ __launch_bounds__(256, 4) void k_main(const float* __restrict__ Q,
                                                 const float* __restrict__ K,
                                                 const float* __restrict__ V,
                                                 const unsigned short* __restrict__ Mt,
                                                 const float* __restrict__ z,
                                                 float* __restrict__ out,
                                                 float* __restrict__ part,
                                                 float* __restrict__ zpart) {
    __shared__ unsigned short smem[128 * 128];  // 32768 B exactly
    if (blockIdx.x < NUPD)
        upd_body(blockIdx.x, K, V, part, zpart, smem);
    else
        out_body(blockIdx.x - NUPD, Q, Mt, z, out, smem);
}

// ---------------------------------------------------------------- k_reduce
__global__ __launch_bounds__(256) void k_reduce(const float* __restrict__ M,
                                                const float* __restrict__ z,
                                                const float* __restrict__ part,
                                                const float* __restrict__ zpart,
                                                float* __restrict__ outM,
                                                float* __restrict__ outz) {
    int idx = blockIdx.x * 256 + threadIdx.x;  // < 524288
    int h = idx >> 14, de = idx & 16383;
    float s = M[idx];
    const float* p = part + (size_t)h * NC * 16384 + de;
#pragma unroll
    for (int c = 0; c < NC; ++c) s += p[(size_t)c * 16384];
    outM[idx] = s;
    if (idx < NH * ND) {
        int hh = idx >> 7, d = idx & 127;
        float sz = z[idx];
        const float* pz = zpart + (size_t)hh * NC * 128 + d;
#pragma unroll
        for (int c = 0; c < NC; ++c) sz += pz[c * 128];
        outz[idx] = sz;
    }
}

extern "C" void kernel_launch(void* const* d_in, const int* in_sizes, int n_in,
                              void* d_out, int out_size, void* d_ws, size_t ws_size,
                              hipStream_t stream) {
    const float* Q = (const float*)d_in[0];
    const float* K = (const float*)d_in[1];
    const float* V = (const float*)d_in[2];
    const float* M = (const float*)d_in[3];
    const float* z = (const float*)d_in[4];

    float* out0 = (float*)d_out;                     // (2,32,4096,128)
    float* outM = out0 + (size_t)NB * NH * NT * ND;  // (32,128,128)
    float* outz = outM + (size_t)NH * ND * ND;       // (32,128)

    unsigned short* Mt = (unsigned short*)d_ws;          // 1 MB
    float* part  = (float*)((char*)d_ws + (1u << 20));   // 16.8 MB
    float* zpart = part + (size_t)NH * NC * ND * ND;     // 128 KB

    k_prep<<<2048, 256, 0, stream>>>(M, Mt);
    k_main<<<NUPD + NOUT, 256, 0, stream>>>(Q, K, V, Mt, z, out0, part, zpart);
    k_reduce<<<(NH * ND * ND) / 256, 256, 0, stream>>>(M, z, part, zpart, outM, outz);
}

// Round 3
// 427.317 us; speedup vs baseline: 1.2424x; 1.2424x over previous
//
#include <hip/hip_runtime.h>
#include <cstdint>
#include <cstddef>

// CompressiveMemory: B=2,H=32,T=4096,D=128 fp32.
// out  = phi(Q)@M / max(phi(Q)@z, eps)      (per b,h)
// Mnew = M + sum_t phiKb(t) outer Vb(t)     (phiKb/Vb are b-means)
// znew = z + sum_t phiKb(t)

typedef __bf16 bf16x8 __attribute__((ext_vector_type(8)));
typedef float  f32x4  __attribute__((ext_vector_type(4)));
typedef unsigned short us8v __attribute__((ext_vector_type(8)));

#define NB 2
#define NH 32
#define NT 4096
#define ND 128
#define NC 8            // split-K chunks for update GEMM
#define TCH (NT / NC)   // 512 t per chunk
#define NUPD (NH * NC)  // 256 update blocks (scheduled first: long poles)
#define NOUT (NB * NH * (NT / 128))  // 2048 out blocks
#define EPSF 1e-6f

__device__ __forceinline__ float phi_f(float x) {
    // elu(x)+1: x>0 -> x+1 ; x<=0 -> exp(x)
    return x > 0.0f ? x + 1.0f : __expf(x);
}

__device__ __forceinline__ unsigned short f2bfn(float f) {
    union { __bf16 h; unsigned short u; } c;
    c.h = (__bf16)f;  // native RNE cvt on gfx950
    return c.u;
}

// native packed convert path: compiler fuses adjacent pairs to v_cvt_pk_bf16_f32
__device__ __forceinline__ bf16x8 cvt8(float4 a, float4 b) {
    bf16x8 r;
    r[0] = (__bf16)a.x; r[1] = (__bf16)a.y; r[2] = (__bf16)a.z; r[3] = (__bf16)a.w;
    r[4] = (__bf16)b.x; r[5] = (__bf16)b.y; r[6] = (__bf16)b.z; r[7] = (__bf16)b.w;
    return r;
}

__device__ __forceinline__ bf16x8 cvt8phi(float4 a, float4 b) {
    bf16x8 r;
    r[0] = (__bf16)phi_f(a.x); r[1] = (__bf16)phi_f(a.y);
    r[2] = (__bf16)phi_f(a.z); r[3] = (__bf16)phi_f(a.w);
    r[4] = (__bf16)phi_f(b.x); r[5] = (__bf16)phi_f(b.y);
    r[6] = (__bf16)phi_f(b.z); r[7] = (__bf16)phi_f(b.w);
    return r;
}

// ---------------------------------------------------------------- k_prep
// Mt[h][e][d] = bf16(M[h][d][e]). M is 2MB -> gather reads are L2-resident.
__global__ __launch_bounds__(256) void k_prep(const float* __restrict__ M,
                                              unsigned short* __restrict__ Mt) {
    int idx = blockIdx.x * 256 + threadIdx.x;  // < 32*128*128
    int h = idx >> 14, rem = idx & 16383;
    int e = rem >> 7, d = rem & 127;
    Mt[idx] = f2bfn(M[(h << 14) + (d << 7) + e]);
}

// ---------------------------------------------------------------- upd body
// C[d][e] = sum_{t in chunk} phiKb[t][d] * Vb[t][e]   (k = t, MFMA)
// Staging accumulates the batch SUM (no 0.5 muls); exact 0.25/0.5
// power-of-2 scales applied at the partial write (numerically identical).
// LDS layout: Kl/Vl [d][t] with XOR swizzle: element (d,t) stored at
// t-group (t>>3) ^ ((d>>2)&7), offset t&7, row stride 64 u16.
// -> ds_write_b128 / ds_read_b128 both near-conflict-free, 16B aligned.
__device__ __forceinline__ void upd_body(int blk, const float* __restrict__ K,
                                         const float* __restrict__ V,
                                         float* __restrict__ part,
                                         float* __restrict__ zpart,
                                         unsigned short* smem) {
    const int tid = threadIdx.x;
    const int h = blk >> 3, ch = blk & 7;
    unsigned short* Kl = smem;          // 128 x 64 (swizzled)
    unsigned short* Vl = smem + 8192;   // 128 x 64

    const size_t bstr = (size_t)NH * NT * ND;
    const float* K0 = K + (size_t)h * NT * ND + (size_t)ch * TCH * ND;
    const float* K1 = K0 + bstr;
    const float* V0 = V + (size_t)h * NT * ND + (size_t)ch * TCH * ND;
    const float* V1 = V0 + bstr;

    const int L = tid & 31, d0 = L << 2, tb = tid >> 5;  // thread: 4 d x 8 t
    const int lane = tid & 63, wave = tid >> 6;
    const int mw = (wave & 1) << 6, nw = (wave >> 1) << 6;
    const int l15 = lane & 15, qd = lane >> 4;
    const int grp = tb ^ (L & 7);  // swizzled t-group for writes ((d>>2)&7 == L&7)

    float zp0 = 0.f, zp1 = 0.f, zp2 = 0.f, zp3 = 0.f;
    f32x4 acc[4][4];
#pragma unroll
    for (int a = 0; a < 4; ++a)
#pragma unroll
        for (int b = 0; b < 4; ++b) acc[a][b] = (f32x4){0.f, 0.f, 0.f, 0.f};

    for (int st = 0; st < TCH / 64; ++st) {
        bf16x8 kpu[4], vpu[4];
#pragma unroll
        for (int i = 0; i < 8; ++i) {  // 8 consecutive t rows
            size_t off = ((size_t)(st * 64 + tb * 8 + i)) * ND + d0;
            float4 a0 = *(const float4*)(K0 + off);
            float4 a1 = *(const float4*)(K1 + off);
            float4 b0 = *(const float4*)(V0 + off);
            float4 b1 = *(const float4*)(V1 + off);
            float p0 = phi_f(a0.x) + phi_f(a1.x);
            float p1 = phi_f(a0.y) + phi_f(a1.y);
            float p2 = phi_f(a0.z) + phi_f(a1.z);
            float p3 = phi_f(a0.w) + phi_f(a1.w);
            zp0 += p0; zp1 += p1; zp2 += p2; zp3 += p3;
            kpu[0][i] = (__bf16)p0; kpu[1][i] = (__bf16)p1;
            kpu[2][i] = (__bf16)p2; kpu[3][i] = (__bf16)p3;
            vpu[0][i] = (__bf16)(b0.x + b1.x);
            vpu[1][i] = (__bf16)(b0.y + b1.y);
            vpu[2][i] = (__bf16)(b0.z + b1.z);
            vpu[3][i] = (__bf16)(b0.w + b1.w);
        }
        __syncthreads();  // previous sub-tile's readers done
#pragma unroll
        for (int j = 0; j < 4; ++j) {
            *(bf16x8*)&Kl[(d0 + j) * 64 + grp * 8] = kpu[j];
            *(bf16x8*)&Vl[(d0 + j) * 64 + grp * 8] = vpu[j];
        }
        __syncthreads();
#pragma unroll
        for (int kk = 0; kk < 2; ++kk) {
            bf16x8 af[4], bv[4];
#pragma unroll
            for (int im = 0; im < 4; ++im) {
                int d = mw + im * 16 + l15;
                int sg = (kk * 4 + qd) ^ ((d >> 2) & 7);
                af[im] = *(const bf16x8*)&Kl[d * 64 + sg * 8];
            }
#pragma unroll
            for (int in = 0; in < 4; ++in) {
                int e = nw + in * 16 + l15;
                int sg = (kk * 4 + qd) ^ ((e >> 2) & 7);
                bv[in] = *(const bf16x8*)&Vl[e * 64 + sg * 8];
            }
#pragma unroll
            for (int im = 0; im < 4; ++im)
#pragma unroll
                for (int in = 0; in < 4; ++in)
                    acc[im][in] = __builtin_amdgcn_mfma_f32_16x16x32_bf16(
                        af[im], bv[in], acc[im][in], 0, 0, 0);
        }
    }

    // z reduction: overlay zacc onto smem (Kl region) once all readers done.
    __syncthreads();
    float* zacc = (float*)smem;
    if (tid < 128) zacc[tid] = 0.0f;
    __syncthreads();
    atomicAdd(&zacc[d0 + 0], zp0);
    atomicAdd(&zacc[d0 + 1], zp1);
    atomicAdd(&zacc[d0 + 2], zp2);
    atomicAdd(&zacc[d0 + 3], zp3);
    __syncthreads();
    if (tid < 128) zpart[((size_t)h * NC + ch) * 128 + tid] = 0.5f * zacc[tid];

    float* pb = part + ((size_t)h * NC + ch) * 16384;
#pragma unroll
    for (int im = 0; im < 4; ++im)
#pragma unroll
        for (int in = 0; in < 4; ++in) {
            int col = nw + in * 16 + l15;
#pragma unroll
            for (int rg = 0; rg < 4; ++rg) {
                int row = mw + im * 16 + qd * 4 + rg;  // d index
                pb[(size_t)row * ND + col] = 0.25f * acc[im][in][rg];
            }
        }
}

// ---------------------------------------------------------------- out body
// C(128x128) = phiQ @ M per (b,h,t-tile). A-fragments straight from global
// (phi in-register); norm = phiQ . z via MFMA against z-broadcast B-frag.
// M^T in LDS, stride 128 u16 + XOR chunk swizzle (chunk c of row e stored at
// c ^ (e&7)): write and read both 2-way max bank aliasing (free), 32768 B.
__device__ __forceinline__ void out_body(int blk, const float* __restrict__ Q,
                                         const unsigned short* __restrict__ Mt,
                                         const float* __restrict__ z,
                                         float* __restrict__ out,
                                         unsigned short* smem) {
    const int tid = threadIdx.x;
    const int tile = blk & 31, bh = blk >> 5, h = bh & 31;
    const float* Qb = Q + ((size_t)bh * NT + (size_t)tile * 128) * ND;
    unsigned short* Bs = smem;  // [e][chunk ^ (e&7)], stride 128 u16

    {
        const us8v* src = (const us8v*)(Mt + (size_t)h * 16384);
#pragma unroll
        for (int i = 0; i < 8; ++i) {
            int idx = i * 256 + tid;  // 16B chunk id
            int e = idx >> 4, d8 = idx & 15;
            *(us8v*)&Bs[e * 128 + ((d8 ^ (e & 7)) << 3)] = src[idx];
        }
    }
    const int lane = tid & 63, wave = tid >> 6;
    const int mw = (wave & 1) << 6, nw = (wave >> 1) << 6;
    const int l15 = lane & 15, qd = lane >> 4;
    const int s7 = l15 & 7;  // e&7 == l15&7 for all our e

    bf16x8 zf[4];  // z broadcast across columns -> accN col = norm(row)
#pragma unroll
    for (int kk = 0; kk < 4; ++kk) {
        const float* zp = z + h * ND + kk * 32 + qd * 8;
        zf[kk] = cvt8(*(const float4*)zp, *(const float4*)(zp + 4));
    }
    __syncthreads();

    f32x4 acc[4][4], accN[4];
#pragma unroll
    for (int a = 0; a < 4; ++a) {
        accN[a] = (f32x4){0.f, 0.f, 0.f, 0.f};
#pragma unroll
        for (int b = 0; b < 4; ++b) acc[a][b] = (f32x4){0.f, 0.f, 0.f, 0.f};
    }

#pragma unroll
    for (int im = 0; im < 4; ++im) {
        int row = mw + im * 16 + l15;
        const float* qr = Qb + (size_t)row * ND;
        bf16x8 af[4];
#pragma unroll
        for (int kk = 0; kk < 4; ++kk) {
            const float* qp = qr + kk * 32 + qd * 8;
            af[kk] = cvt8phi(*(const float4*)qp, *(const float4*)(qp + 4));
        }
#pragma unroll
        for (int kk = 0; kk < 4; ++kk)
            accN[im] = __builtin_amdgcn_mfma_f32_16x16x32_bf16(
                af[kk], zf[kk], accN[im], 0, 0, 0);
#pragma unroll
        for (int in = 0; in < 4; ++in) {
            int e = nw + in * 16 + l15;
#pragma unroll
            for (int kk = 0; kk < 4; ++kk) {
                bf16x8 bv = *(const bf16x8*)&Bs[e * 128 + ((((kk << 2) | qd) ^ s7) << 3)];
                acc[im][in] = __builtin_amdgcn_mfma_f32_16x16x32_bf16(
                    af[kk], bv, acc[im][in], 0, 0, 0);
            }
        }
    }

    float* outb = out + ((size_t)bh * NT + (size_t)tile * 128) * ND;
#pragma unroll
    for (int im = 0; im < 4; ++im) {
#pragma unroll
        for (int rg = 0; rg < 4; ++rg) {
            float inv = __builtin_amdgcn_rcpf(fmaxf(accN[im][rg], EPSF));
            int row = mw + im * 16 + qd * 4 + rg;
#pragma unroll
            for (int in = 0; in < 4; ++in) {
                int col = nw + in * 16 + l15;
                outb[(size_t)row * ND + col] = acc[im][in][rg] * inv;
            }
        }
    }
}

// ---------------------------------------------------------------- k_main
// NOTE: plain (256) — round 2 showed (256,4) caps VGPR at 64 and spills
// acc[4][4] to scratch (+270 MB HBM traffic, 162->274 us). Never pin waves
// here; the allocator's 128-VGPR choice is the fast point.
__global__ __launch_bounds__(256) void k_main(const float* __restrict__ Q,
                                              const float* __restrict__ K,
                                              const float* __restrict__ V,
                                              const unsigned short* __restrict__ Mt,
                                              const float* __restrict__ z,
                                              float* __restrict__ out,
                                              float* __restrict__ part,
                                              float* __restrict__ zpart) {
    __shared__ unsigned short smem[128 * 128];  // 32768 B exactly
    if (blockIdx.x < NUPD)
        upd_body(blockIdx.x, K, V, part, zpart, smem);
    else
        out_body(blockIdx.x - NUPD, Q, Mt, z, out, smem);
}

// ---------------------------------------------------------------- k_reduce
__global__ __launch_bounds__(256) void k_reduce(const float* __restrict__ M,
                                                const float* __restrict__ z,
                                                const float* __restrict__ part,
                                                const float* __restrict__ zpart,
                                                float* __restrict__ outM,
                                                float* __restrict__ outz) {
    int idx = blockIdx.x * 256 + threadIdx.x;  // < 524288
    int h = idx >> 14, de = idx & 16383;
    float s = M[idx];
    const float* p = part + (size_t)h * NC * 16384 + de;
#pragma unroll
    for (int c = 0; c < NC; ++c) s += p[(size_t)c * 16384];
    outM[idx] = s;
    if (idx < NH * ND) {
        int hh = idx >> 7, d = idx & 127;
        float sz = z[idx];
        const float* pz = zpart + (size_t)hh * NC * 128 + d;
#pragma unroll
        for (int c = 0; c < NC; ++c) sz += pz[c * 128];
        outz[idx] = sz;
    }
}

extern "C" void kernel_launch(void* const* d_in, const int* in_sizes, int n_in,
                              void* d_out, int out_size, void* d_ws, size_t ws_size,
                              hipStream_t stream) {
    const float* Q = (const float*)d_in[0];
    const float* K = (const float*)d_in[1];
    const float* V = (const float*)d_in[2];
    const float* M = (const float*)d_in[3];
    const float* z = (const float*)d_in[4];

    float* out0 = (float*)d_out;                     // (2,32,4096,128)
    float* outM = out0 + (size_t)NB * NH * NT * ND;  // (32,128,128)
    float* outz = outM + (size_t)NH * ND * ND;       // (32,128)

    unsigned short* Mt = (unsigned short*)d_ws;          // 1 MB
    float* part  = (float*)((char*)d_ws + (1u << 20));   // 16.8 MB
    float* zpart = part + (size_t)NH * NC * ND * ND;     // 128 KB

    k_prep<<<2048, 256, 0, stream>>>(M, Mt);
    k_main<<<NUPD + NOUT, 256, 0, stream>>>(Q, K, V, Mt, z, out0, part, zpart);
    k_reduce<<<(NH * ND * ND) / 256, 256, 0, stream>>>(M, z, part, zpart, outM, outz);
}